// Round 4
// baseline (1031.985 us; speedup 1.0000x reference)
//
#include <hip/hip_runtime.h>
#include <hip/hip_bf16.h>
#include <hip/hip_fp16.h>

// LSTM_Encoder pipeline (dtype-agnostic: runtime-sniffs fp32 vs bf16 inputs):
//   setup (fused embed+pack+pairs+senlen; sniff runs ONCE per block on thread 0, LDS-broadcast)
//   gemm_bt(x0,Wc0) -> xg    (MFMA bf16, M=4096 N=1600 K=576; 128x128 tile, BK=64,
//                             reg-prefetch pipeline; last N-tile is 64-wide via 'full' branch)
//   rec(layer0)              (64 blocks = batch x dir, VGPR-resident f16 weights, ONE barrier
//                             per step: neuron n's 4 gates in lanes 2n/2n+1, shfl_xor exchange,
//                             no gsh; xg prefetched one step ahead; threads>=400 pad x1)
//   gemm_bt(x1,Wc1) -> xg    (K=448 padded)
//   rec(layer1) -> hs1 (f32)
//   span                     (grid transposed (bb,chunk): 32%8==0 pins batch bb to XCD bb%8,
//                             hs1 slice 816 KB/XCD stays L2-resident; regular 16B stores —
//                             NT stores measured ~+60us on this stream (round1), do not retry)

typedef unsigned short u16;
typedef unsigned int u32;
typedef short shortx8 __attribute__((ext_vector_type(8)));
typedef float floatx4 __attribute__((ext_vector_type(4)));
typedef float fx4 __attribute__((ext_vector_type(4)));
typedef unsigned int ux4 __attribute__((ext_vector_type(4)));
typedef _Float16 half2v __attribute__((ext_vector_type(2)));

#define B_ 32
#define L_ 128
#define H_ 200
#define K0P 576
#define K1P 448
#define NG 1600
#define NPAIR 8001
#define SPAN_ELEMS 102412800  // 32*8001*400

#define EMB_BLKS 1024
#define PACK_ELEMS (1600 * K0P + 1600 * K1P + 1600 + 1600 + 640000)
#define PACK_BLKS ((PACK_ELEMS + 255) / 256)

__device__ __forceinline__ float bf2f(u16 v) {
  u32 u = ((u32)v) << 16;
  return __builtin_bit_cast(float, u);
}
__device__ __forceinline__ u16 f2bf(float f) {
  __hip_bfloat16 h = __float2bfloat16(f);
  return __builtin_bit_cast(u16, h);
}
__device__ __forceinline__ float loadF(const void* p, int idx, int isf32) {
  return isf32 ? ((const float*)p)[idx] : bf2f(((const u16*)p)[idx]);
}
__device__ __forceinline__ float dot2h(u32 w, u32 h, float acc) {
#if __has_builtin(__builtin_amdgcn_fdot2)
  return __builtin_amdgcn_fdot2(__builtin_bit_cast(half2v, w),
                                __builtin_bit_cast(half2v, h), acc, false);
#else
  half2v a = __builtin_bit_cast(half2v, w), b = __builtin_bit_cast(half2v, h);
  return acc + (float)a.x * (float)b.x + (float)a.y * (float)b.y;
#endif
}
__device__ __forceinline__ float sigf(float x) { return 1.f / (1.f + __expf(-x)); }
__device__ __forceinline__ float tanhff(float x) {
  x = fminf(fmaxf(x, -15.f), 15.f);
  float e = __expf(-2.f * x);
  return (1.f - e) / (1.f + e);
}

// dtype sniff: |bf16| >= 32 never happens for 0.1*N(0,1) bf16 data, ~48% for raw fp32 halves.
__device__ __forceinline__ int sniff(const u16* p) {
  int big = 0;
#pragma unroll 16
  for (int i = 0; i < 128; ++i) {
    int e = (p[i] >> 7) & 0xFF;
    big += (e >= 0x84);
  }
  return (big >= 4) ? 1 : 0;
}

// ---------- fused setup: embed (blocks 0..1023) / pack / pairs+senlen+flag (last block) ----------
// sniff runs once per block (thread 0) and is LDS-broadcast: round-0 cost, round-1 fusion.

__global__ void setup_kernel(const int* __restrict__ lang, const int* __restrict__ word,
                             const int* __restrict__ pos, const int* __restrict__ dep,
                             const int* __restrict__ ent, const int* __restrict__ iob,
                             const void* __restrict__ El, const void* __restrict__ Ew,
                             const void* __restrict__ Ep, const void* __restrict__ Ed,
                             const void* __restrict__ Ee, const void* __restrict__ Ei,
                             const void* __restrict__ Wih0, const void* __restrict__ Whh0,
                             const void* __restrict__ bih0, const void* __restrict__ bhh0,
                             const void* __restrict__ Wih1, const void* __restrict__ Whh1,
                             const void* __restrict__ bih1, const void* __restrict__ bhh1,
                             u16* __restrict__ x0, u16* __restrict__ Wc0, u16* __restrict__ Wc1,
                             float* __restrict__ bias0, float* __restrict__ bias1,
                             u16* __restrict__ Whf, int* __restrict__ flag,
                             int* __restrict__ pa, int* __restrict__ pb, void* __restrict__ out) {
  __shared__ int sflag;
  int blk = blockIdx.x, tid = threadIdx.x;
  if (tid == 0) sflag = sniff((const u16*)Ew);
  __syncthreads();
  int isf32 = sflag;

  if (blk < EMB_BLKS) {  // embedding gather: 4 rows per block, row = l*32 + b (x[l][b] = emb[b][l])
    int row = blk * 4 + (tid >> 6);
    int lane = tid & 63;
    int l = row >> 5, b = row & 31;
    int io = b * L_ + l;
    int li = lang[io], wi = word[io], pi = pos[io], di = dep[io], ei = ent[io], ii = iob[io];
    for (int c = lane; c < K0P; c += 64) {
      float v = 0.f;
      if (c < 50) v = loadF(El, li * 50 + c, isf32);
      else if (c < 350) v = loadF(Ew, wi * 300 + (c - 50), isf32);
      else if (c < 400) v = loadF(Ep, pi * 50 + (c - 350), isf32);
      else if (c < 450) v = loadF(Ed, di * 50 + (c - 400), isf32);
      else if (c < 500) v = loadF(Ee, ei * 50 + (c - 450), isf32);
      else if (c < 550) v = loadF(Ei, ii * 50 + (c - 500), isf32);
      x0[row * K0P + c] = f2bf(v);
    }
    return;
  }
  blk -= EMB_BLKS;

  if (blk < PACK_BLKS) {  // weight repack
    int idx = blk * 256 + tid;
    if (idx < 1600 * K0P) {  // Wc0: rows (dir*800+g), cols padded 550->576
      int r = idx / K0P, c = idx - r * K0P;
      Wc0[idx] = (c < 550) ? f2bf(loadF(Wih0, r * 550 + c, isf32)) : (u16)0;
      return;
    }
    idx -= 1600 * K0P;
    if (idx < 1600 * K1P) {  // Wc1: cols padded 400->448
      int r = idx / K1P, c = idx - r * K1P;
      Wc1[idx] = (c < 400) ? f2bf(loadF(Wih1, r * 400 + c, isf32)) : (u16)0;
      return;
    }
    idx -= 1600 * K1P;
    if (idx < 1600) { bias0[idx] = loadF(bih0, idx, isf32) + loadF(bhh0, idx, isf32); return; }
    idx -= 1600;
    if (idx < 1600) { bias1[idx] = loadF(bih1, idx, isf32) + loadF(bhh1, idx, isf32); return; }
    idx -= 1600;
    if (idx < 640000) {  // Whh -> f16, [layer][dir][800][200]
      float s = (idx < 320000) ? loadF(Whh0, idx, isf32) : loadF(Whh1, idx - 320000, isf32);
      _Float16 h = (_Float16)s;
      Whf[idx] = __builtin_bit_cast(u16, h);
    }
    return;
  }

  // final block: flag (for span), pairs, sen_lens
  if (tid == 0) *flag = isf32;
  if (tid < 126) {
    int a = tid;
    int off = a * 126 - a * (a - 1) / 2;
    for (int b = a + 1; b <= 126; ++b) {
      pa[off] = a;
      pb[off] = b;
      ++off;
    }
  }
  if (tid >= 128 && tid < 128 + B_) {
    int b = tid - 128;
    int cnt = 0;
    for (int l = 0; l < L_; ++l) cnt += (word[b * L_ + l] != 0);
    float v = (float)(cnt - 2);
    if (isf32) ((float*)out)[SPAN_ELEMS + b] = v;
    else ((u16*)out)[SPAN_ELEMS + b] = f2bf(v);
  }
}

// ---------- GEMM: C[M,1600](bf16) = A[M,Ks](bf16) * W[1600,Ks]^T + bias ----------
// 128x128 tile (8 waves, 512 thr), BK=64, reg-prefetch pipeline. Grid x=13 N-tiles:
// tiles 0..11 full 128 wide, tile 12 is 64 wide (static 4-ns branch; OOB B-tile rows
// read adjacent workspace — in-bounds, never consumed). Accumulation order identical
// to the 64x64 version (bit-identical output).

__global__ __launch_bounds__(512) void gemm_bt(const u16* __restrict__ A, const u16* __restrict__ W,
                                               const float* __restrict__ bias, u16* __restrict__ C,
                                               int Ks) {
  __shared__ __align__(16) u16 As[128 * 72];  // stride 72 shorts = 144 B (8 start-banks, b128-clean)
  __shared__ __align__(16) u16 Bs[128 * 72];
  int tid = threadIdx.x;
  int n0 = blockIdx.x * 128, m0 = blockIdx.y * 128;
  int lane = tid & 63, wv = tid >> 6, ln = lane & 15, quad = lane >> 4;
  floatx4 acc[8] = {{0.f, 0.f, 0.f, 0.f}, {0.f, 0.f, 0.f, 0.f}, {0.f, 0.f, 0.f, 0.f}, {0.f, 0.f, 0.f, 0.f},
                    {0.f, 0.f, 0.f, 0.f}, {0.f, 0.f, 0.f, 0.f}, {0.f, 0.f, 0.f, 0.f}, {0.f, 0.f, 0.f, 0.f}};
  int arow = tid >> 2, acs = (tid & 3) * 8;  // thread covers cols [acs,acs+8) and [acs+32,acs+40)
  const u16* Ag = A + (size_t)(m0 + arow) * Ks + acs;
  const u16* Wg = W + (size_t)(n0 + arow) * Ks + acs;
  int asb = arow * 72 + acs;
  uint4 ra0 = *(const uint4*)(Ag);
  uint4 ra1 = *(const uint4*)(Ag + 32);
  uint4 rb0 = *(const uint4*)(Wg);
  uint4 rb1 = *(const uint4*)(Wg + 32);
  const bool full = (n0 + 128 <= NG);  // uniform per block
  for (int k0 = 0; k0 < Ks; k0 += 64) {
    *(uint4*)&As[asb] = ra0;
    *(uint4*)&As[asb + 32] = ra1;
    *(uint4*)&Bs[asb] = rb0;
    *(uint4*)&Bs[asb + 32] = rb1;
    __syncthreads();
    if (k0 + 64 < Ks) {  // prefetch next chunk; consumed at next iteration's store
      ra0 = *(const uint4*)(Ag + k0 + 64);
      ra1 = *(const uint4*)(Ag + k0 + 96);
      rb0 = *(const uint4*)(Wg + k0 + 64);
      rb1 = *(const uint4*)(Wg + k0 + 96);
    }
    int abase = (wv * 16 + ln) * 72;
    if (full) {
#pragma unroll
      for (int ks = 0; ks < 2; ++ks) {
        int ko = ks * 32 + quad * 8;
        shortx8 af = *(const shortx8*)&As[abase + ko];
#pragma unroll
        for (int ns = 0; ns < 8; ++ns) {
          shortx8 bf = *(const shortx8*)&Bs[(ns * 16 + ln) * 72 + ko];
          acc[ns] = __builtin_amdgcn_mfma_f32_16x16x32_bf16(af, bf, acc[ns], 0, 0, 0);
        }
      }
    } else {
#pragma unroll
      for (int ks = 0; ks < 2; ++ks) {
        int ko = ks * 32 + quad * 8;
        shortx8 af = *(const shortx8*)&As[abase + ko];
#pragma unroll
        for (int ns = 0; ns < 4; ++ns) {
          shortx8 bf = *(const shortx8*)&Bs[(ns * 16 + ln) * 72 + ko];
          acc[ns] = __builtin_amdgcn_mfma_f32_16x16x32_bf16(af, bf, acc[ns], 0, 0, 0);
        }
      }
    }
    __syncthreads();
  }
  int rbase = m0 + wv * 16 + quad * 4;  // C/D: col=lane&15, row=quad*4+reg (m89-verified)
  if (full) {
#pragma unroll
    for (int ns = 0; ns < 8; ++ns) {
      int cg = n0 + ns * 16 + ln;
      float bv = bias[cg];
#pragma unroll
      for (int r = 0; r < 4; ++r) {
        C[(size_t)(rbase + r) * NG + cg] = f2bf(acc[ns][r] + bv);
      }
    }
  } else {
#pragma unroll
    for (int ns = 0; ns < 4; ++ns) {
      int cg = n0 + ns * 16 + ln;
      float bv = bias[cg];
#pragma unroll
      for (int r = 0; r < 4; ++r) {
        C[(size_t)(rbase + r) * NG + cg] = f2bf(acc[ns][r] + bv);
      }
    }
  }
}

// ---------- recurrence: 64 blocks = (batch, dir), weights VGPR-resident, ONE barrier/step ----
// Row mapping: thread t -> neuron n=t>>1, half hi=t&1; rows rA=hi*400+n (i or gg),
// rB=rA+200 (f or o). After the dot chains, the pair exchanges its two gate values via
// shfl_xor(1) (in-wave, no barrier, no gsh LDS). Both lanes compute identical c,h;
// even lane writes hsh[n] (f16, for next step's broadcast), odd lane does the global
// x1/hs store. Threads >=400 (idle) zero-pad x1 cols 400..447 for the K=448 GEMM.
// Per-row dot order and activation math are bit-identical to the 2-barrier version.

__global__ __launch_bounds__(448, 2) void rec_kernel(const u16* __restrict__ xg, const u16* __restrict__ Whf,
                                                     int layer, u16* __restrict__ x1, float* __restrict__ hs) {
  int tid = threadIdx.x;
  int batch = blockIdx.x >> 1, dir = blockIdx.x & 1;
  __shared__ __align__(16) u16 hsh[H_];   // h as f16
  uint4 wA[25], wB[25];                   // 2 rows x 200 f16 = 200 VGPRs
  int n = tid >> 1, hi = tid & 1;
  int rA = hi * 400 + n;                  // even: i-row, odd: gg-row
  int rB = rA + 200;                      // even: f-row, odd: o-row
  if (tid < 400) {
    const uint4* wa = (const uint4*)(Whf + (size_t)((layer * 2 + dir) * 800 + rA) * 200);
    const uint4* wb = (const uint4*)(Whf + (size_t)((layer * 2 + dir) * 800 + rB) * 200);
#pragma unroll
    for (int i = 0; i < 25; ++i) { wA[i] = wa[i]; wB[i] = wb[i]; }
  }
  float cst = 0.f;
  if (tid < H_) hsh[tid] = 0;
  int rstep = (dir ? -B_ : B_) * NG;
  const u16* xr = xg + (size_t)((dir ? (L_ - 1) * B_ : 0) + batch) * NG + dir * 800;
  float a0 = 0.f, a1 = 0.f;
  if (tid < 400) { a0 = bf2f(xr[rA]); a1 = bf2f(xr[rB]); }
  __syncthreads();
  for (int t = 0; t < L_; ++t) {
    int tt = dir ? (L_ - 1 - t) : t;
    int orow = tt * B_ + batch;
    float n0 = 0.f, n1 = 0.f;
    if (tid < 400) {
      if (t + 1 < L_) {  // prefetch next step's xg before the dot chain
        const u16* xn = xr + (ptrdiff_t)(t + 1) * rstep;
        n0 = bf2f(xn[rA]);
        n1 = bf2f(xn[rB]);
      }
      float c0 = 0.f, c1 = 0.f;  // second accumulator pair (shorter dep chains)
      const uint4* hv4 = (const uint4*)hsh;
#pragma unroll
      for (int kk = 0; kk < 25; kk += 2) {
        uint4 hv = hv4[kk];  // broadcast read (free)
        a0 = dot2h(wA[kk].x, hv.x, a0);
        a0 = dot2h(wA[kk].y, hv.y, a0);
        a0 = dot2h(wA[kk].z, hv.z, a0);
        a0 = dot2h(wA[kk].w, hv.w, a0);
        a1 = dot2h(wB[kk].x, hv.x, a1);
        a1 = dot2h(wB[kk].y, hv.y, a1);
        a1 = dot2h(wB[kk].z, hv.z, a1);
        a1 = dot2h(wB[kk].w, hv.w, a1);
        if (kk + 1 < 25) {
          uint4 hw = hv4[kk + 1];
          c0 = dot2h(wA[kk + 1].x, hw.x, c0);
          c0 = dot2h(wA[kk + 1].y, hw.y, c0);
          c0 = dot2h(wA[kk + 1].z, hw.z, c0);
          c0 = dot2h(wA[kk + 1].w, hw.w, c0);
          c1 = dot2h(wB[kk + 1].x, hw.x, c1);
          c1 = dot2h(wB[kk + 1].y, hw.y, c1);
          c1 = dot2h(wB[kk + 1].z, hw.z, c1);
          c1 = dot2h(wB[kk + 1].w, hw.w, c1);
        }
      }
      float gA = a0 + c0;  // even: i_n, odd: gg_n
      float gB = a1 + c1;  // even: f_n, odd: o_n
      float oA = __shfl_xor(gA, 1, 64);
      float oB = __shfl_xor(gB, 1, 64);
      float gi = hi ? oA : gA;
      float gf = hi ? oB : gB;
      float gg = hi ? gA : oA;
      float go = hi ? gB : oB;
      cst = sigf(gf) * cst + sigf(gi) * tanhff(gg);  // replicated on both lanes of the pair
      float h = sigf(go) * tanhff(cst);
      if (hi == 0) {
        _Float16 hh = (_Float16)h;
        hsh[n] = __builtin_bit_cast(u16, hh);
      } else if (layer == 0) {
        x1[(size_t)orow * K1P + dir * H_ + n] = f2bf(h);
      } else {
        hs[(size_t)orow * 400 + dir * H_ + n] = h;
      }
    } else if (layer == 0) {  // threads 400..447: zero-pad x1 cols 400..447
      x1[(size_t)orow * K1P + 400 + (tid - 400)] = (u16)0;
    }
    a0 = n0;
    a1 = n1;
    __syncthreads();  // hsh[n] visible before next step's broadcast reads
  }
}

// ---------- span output: out[bb][p][0:400], 8 cols per thread (16B loads/stores) ----------
// Grid is (bb=32, chunk=126): linear block id = bb + 32*chunk, and 32%8==0, so XCD = bb%8.
// Each XCD serves only 4 batches -> 816 KB of hs1 slices, L2-resident across all 126 chunks.

__global__ __launch_bounds__(256) void span_kernel(const float* __restrict__ hs, const int* __restrict__ pa,
                                                   const int* __restrict__ pb, void* __restrict__ outp,
                                                   const int* __restrict__ flag) {
  int bb = blockIdx.x;
  int p0 = blockIdx.y * 64;
  int isf32 = *flag;
  for (int idx = threadIdx.x; idx < 64 * 50; idx += 256) {
    int pr = idx / 50;           // pair within block chunk
    int q = idx - pr * 50;       // 8-col group: cols 8q..8q+7
    int p = p0 + pr;
    if (p >= NPAIR) continue;
    int a = pa[p], b = pb[p];
    int fwd = (q < 25);          // cols<200 -> f[b]-f[a]; cols>=200 -> bw[a+1]-bw[b+1]
    int r1 = fwd ? b : (a + 1);
    int r2 = fwd ? a : (b + 1);
    int col = q * 8;
    const fx4* h1 = (const fx4*)(hs + (size_t)(r1 * B_ + bb) * 400 + col);
    const fx4* h2 = (const fx4*)(hs + (size_t)(r2 * B_ + bb) * 400 + col);
    fx4 d0 = h1[0] - h2[0];
    fx4 d1 = h1[1] - h2[1];
    if (isf32) {
      fx4* o = (fx4*)outp + (size_t)(bb * NPAIR + p) * 100 + q * 2;
      o[0] = d0;
      o[1] = d1;
    } else {
      ux4 w;
      w.x = (u32)f2bf(d0.x) | ((u32)f2bf(d0.y) << 16);
      w.y = (u32)f2bf(d0.z) | ((u32)f2bf(d0.w) << 16);
      w.z = (u32)f2bf(d1.x) | ((u32)f2bf(d1.y) << 16);
      w.w = (u32)f2bf(d1.z) | ((u32)f2bf(d1.w) << 16);
      ((ux4*)outp)[(size_t)(bb * NPAIR + p) * 50 + q] = w;
    }
  }
}

// ---------- launch ----------

extern "C" void kernel_launch(void* const* d_in, const int* in_sizes, int n_in,
                              void* d_out, int out_size, void* d_ws, size_t ws_size,
                              hipStream_t stream) {
  const int* lang = (const int*)d_in[0];
  const int* word = (const int*)d_in[1];
  const int* pos = (const int*)d_in[2];
  const int* dep = (const int*)d_in[3];
  const int* ent = (const int*)d_in[4];
  const int* iob = (const int*)d_in[5];

  char* ws = (char*)d_ws;
  int* flag = (int*)(ws + 0);
  int* pa = (int*)(ws + 4096);
  int* pb = (int*)(ws + 36864);
  u16* x0 = (u16*)(ws + 69632);            // 4096x576 bf16 (4,718,592 B)
  u16* x1 = x0;                            // aliased: x0 dead after gemm0; x1 = 4096x448 bf16 fits
  u16* Wc0 = (u16*)(ws + 4788224);         // 1600x576 bf16
  u16* Wc1 = (u16*)(ws + 6631424);         // 1600x448 bf16
  float* bias0 = (float*)(ws + 8065024);   // 1600 f32
  float* bias1 = (float*)(ws + 8071424);
  u16* Whf = (u16*)(ws + 8077824);         // 2x2x800x200 f16
  float* hs1 = (float*)(ws + 9357824);     // 4096x400 f32
  u16* xg = (u16*)(ws + 15911424);         // 4096x1600 bf16 (end ~29.0 MB)

  hipLaunchKernelGGL(setup_kernel, dim3(EMB_BLKS + PACK_BLKS + 1), dim3(256), 0, stream,
                     lang, word, pos, dep, ent, iob,
                     d_in[6], d_in[7], d_in[8], d_in[9], d_in[10], d_in[11],
                     d_in[12], d_in[13], d_in[14], d_in[15],
                     d_in[16], d_in[17], d_in[18], d_in[19],
                     x0, Wc0, Wc1, bias0, bias1, Whf, flag, pa, pb, d_out);
  hipLaunchKernelGGL(gemm_bt, dim3(13, 32), dim3(512), 0, stream, x0, Wc0, bias0, xg, K0P);
  hipLaunchKernelGGL(rec_kernel, dim3(64), dim3(448), 0, stream, xg, Whf, 0, x1, hs1);
  hipLaunchKernelGGL(gemm_bt, dim3(13, 32), dim3(512), 0, stream, x1, Wc1, bias1, xg, K1P);
  hipLaunchKernelGGL(rec_kernel, dim3(64), dim3(448), 0, stream, xg, Whf, 1, x1, hs1);
  hipLaunchKernelGGL(span_kernel, dim3(32, 126), dim3(256), 0, stream, hs1, pa, pb, d_out, flag);
}

// Round 5
// 925.691 us; speedup vs baseline: 1.1148x; 1.1148x over previous
//
#include <hip/hip_runtime.h>
#include <hip/hip_bf16.h>
#include <hip/hip_fp16.h>

// LSTM_Encoder pipeline (dtype-agnostic: runtime-sniffs fp32 vs bf16 inputs):
//   setup (fused embed+pack+pairs+senlen; sniff runs ONCE per block on thread 0, LDS-broadcast)
//   gemm_bt(x0,Wc0) -> xg    (MFMA bf16, M=4096 N=1600 K=576; 128x128 tile, BK=64,
//                             reg-prefetch pipeline; last N-tile is 64-wide via 'full' branch)
//   rec(layer0)              (64 blocks = batch x dir, VGPR-resident f16 weights,
//                             xg prefetched one step ahead; idle lanes zero-pad x1 cols 400..447.
//                             NOTE: launch_bounds(448) with NO min-waves — the (448,2) variant
//                             caps VGPR at 256 and rec carries ~240 live; round-4's pair-lane
//                             restructure (+~10 regs) spilled and cost +109us. 64 blocks on
//                             256 CUs never co-reside, so the cap was pure downside.)
//   gemm_bt(x1,Wc1) -> xg    (K=448 padded)
//   rec(layer1) -> hs1 (f32)
//   span                     (grid transposed (bb,chunk): 32%8==0 pins batch bb to XCD bb%8,
//                             hs1 slice 816 KB/XCD stays L2-resident; regular 16B stores —
//                             NT stores measured ~+60us on this stream (round1), do not retry)

typedef unsigned short u16;
typedef unsigned int u32;
typedef short shortx8 __attribute__((ext_vector_type(8)));
typedef float floatx4 __attribute__((ext_vector_type(4)));
typedef float fx4 __attribute__((ext_vector_type(4)));
typedef unsigned int ux4 __attribute__((ext_vector_type(4)));
typedef _Float16 half2v __attribute__((ext_vector_type(2)));

#define B_ 32
#define L_ 128
#define H_ 200
#define K0P 576
#define K1P 448
#define NG 1600
#define NPAIR 8001
#define SPAN_ELEMS 102412800  // 32*8001*400

#define EMB_BLKS 1024
#define PACK_ELEMS (1600 * K0P + 1600 * K1P + 1600 + 1600 + 640000)
#define PACK_BLKS ((PACK_ELEMS + 255) / 256)

__device__ __forceinline__ float bf2f(u16 v) {
  u32 u = ((u32)v) << 16;
  return __builtin_bit_cast(float, u);
}
__device__ __forceinline__ u16 f2bf(float f) {
  __hip_bfloat16 h = __float2bfloat16(f);
  return __builtin_bit_cast(u16, h);
}
__device__ __forceinline__ float loadF(const void* p, int idx, int isf32) {
  return isf32 ? ((const float*)p)[idx] : bf2f(((const u16*)p)[idx]);
}
__device__ __forceinline__ float dot2h(u32 w, u32 h, float acc) {
#if __has_builtin(__builtin_amdgcn_fdot2)
  return __builtin_amdgcn_fdot2(__builtin_bit_cast(half2v, w),
                                __builtin_bit_cast(half2v, h), acc, false);
#else
  half2v a = __builtin_bit_cast(half2v, w), b = __builtin_bit_cast(half2v, h);
  return acc + (float)a.x * (float)b.x + (float)a.y * (float)b.y;
#endif
}
__device__ __forceinline__ float sigf(float x) { return 1.f / (1.f + __expf(-x)); }
__device__ __forceinline__ float tanhff(float x) {
  x = fminf(fmaxf(x, -15.f), 15.f);
  float e = __expf(-2.f * x);
  return (1.f - e) / (1.f + e);
}

// dtype sniff: |bf16| >= 32 never happens for 0.1*N(0,1) bf16 data, ~48% for raw fp32 halves.
__device__ __forceinline__ int sniff(const u16* p) {
  int big = 0;
#pragma unroll 16
  for (int i = 0; i < 128; ++i) {
    int e = (p[i] >> 7) & 0xFF;
    big += (e >= 0x84);
  }
  return (big >= 4) ? 1 : 0;
}

// ---------- fused setup: embed (blocks 0..1023) / pack / pairs+senlen+flag (last block) ----------
// sniff runs once per block (thread 0) and is LDS-broadcast: round-0 cost, round-1 fusion.

__global__ void setup_kernel(const int* __restrict__ lang, const int* __restrict__ word,
                             const int* __restrict__ pos, const int* __restrict__ dep,
                             const int* __restrict__ ent, const int* __restrict__ iob,
                             const void* __restrict__ El, const void* __restrict__ Ew,
                             const void* __restrict__ Ep, const void* __restrict__ Ed,
                             const void* __restrict__ Ee, const void* __restrict__ Ei,
                             const void* __restrict__ Wih0, const void* __restrict__ Whh0,
                             const void* __restrict__ bih0, const void* __restrict__ bhh0,
                             const void* __restrict__ Wih1, const void* __restrict__ Whh1,
                             const void* __restrict__ bih1, const void* __restrict__ bhh1,
                             u16* __restrict__ x0, u16* __restrict__ Wc0, u16* __restrict__ Wc1,
                             float* __restrict__ bias0, float* __restrict__ bias1,
                             u16* __restrict__ Whf, int* __restrict__ flag,
                             int* __restrict__ pa, int* __restrict__ pb, void* __restrict__ out) {
  __shared__ int sflag;
  int blk = blockIdx.x, tid = threadIdx.x;
  if (tid == 0) sflag = sniff((const u16*)Ew);
  __syncthreads();
  int isf32 = sflag;

  if (blk < EMB_BLKS) {  // embedding gather: 4 rows per block, row = l*32 + b (x[l][b] = emb[b][l])
    int row = blk * 4 + (tid >> 6);
    int lane = tid & 63;
    int l = row >> 5, b = row & 31;
    int io = b * L_ + l;
    int li = lang[io], wi = word[io], pi = pos[io], di = dep[io], ei = ent[io], ii = iob[io];
    for (int c = lane; c < K0P; c += 64) {
      float v = 0.f;
      if (c < 50) v = loadF(El, li * 50 + c, isf32);
      else if (c < 350) v = loadF(Ew, wi * 300 + (c - 50), isf32);
      else if (c < 400) v = loadF(Ep, pi * 50 + (c - 350), isf32);
      else if (c < 450) v = loadF(Ed, di * 50 + (c - 400), isf32);
      else if (c < 500) v = loadF(Ee, ei * 50 + (c - 450), isf32);
      else if (c < 550) v = loadF(Ei, ii * 50 + (c - 500), isf32);
      x0[row * K0P + c] = f2bf(v);
    }
    return;
  }
  blk -= EMB_BLKS;

  if (blk < PACK_BLKS) {  // weight repack
    int idx = blk * 256 + tid;
    if (idx < 1600 * K0P) {  // Wc0: rows (dir*800+g), cols padded 550->576
      int r = idx / K0P, c = idx - r * K0P;
      Wc0[idx] = (c < 550) ? f2bf(loadF(Wih0, r * 550 + c, isf32)) : (u16)0;
      return;
    }
    idx -= 1600 * K0P;
    if (idx < 1600 * K1P) {  // Wc1: cols padded 400->448
      int r = idx / K1P, c = idx - r * K1P;
      Wc1[idx] = (c < 400) ? f2bf(loadF(Wih1, r * 400 + c, isf32)) : (u16)0;
      return;
    }
    idx -= 1600 * K1P;
    if (idx < 1600) { bias0[idx] = loadF(bih0, idx, isf32) + loadF(bhh0, idx, isf32); return; }
    idx -= 1600;
    if (idx < 1600) { bias1[idx] = loadF(bih1, idx, isf32) + loadF(bhh1, idx, isf32); return; }
    idx -= 1600;
    if (idx < 640000) {  // Whh -> f16, [layer][dir][800][200]
      float s = (idx < 320000) ? loadF(Whh0, idx, isf32) : loadF(Whh1, idx - 320000, isf32);
      _Float16 h = (_Float16)s;
      Whf[idx] = __builtin_bit_cast(u16, h);
    }
    return;
  }

  // final block: flag (for span), pairs, sen_lens
  if (tid == 0) *flag = isf32;
  if (tid < 126) {
    int a = tid;
    int off = a * 126 - a * (a - 1) / 2;
    for (int b = a + 1; b <= 126; ++b) {
      pa[off] = a;
      pb[off] = b;
      ++off;
    }
  }
  if (tid >= 128 && tid < 128 + B_) {
    int b = tid - 128;
    int cnt = 0;
    for (int l = 0; l < L_; ++l) cnt += (word[b * L_ + l] != 0);
    float v = (float)(cnt - 2);
    if (isf32) ((float*)out)[SPAN_ELEMS + b] = v;
    else ((u16*)out)[SPAN_ELEMS + b] = f2bf(v);
  }
}

// ---------- GEMM: C[M,1600](bf16) = A[M,Ks](bf16) * W[1600,Ks]^T + bias ----------
// 128x128 tile (8 waves, 512 thr), BK=64, reg-prefetch pipeline. Grid x=13 N-tiles:
// tiles 0..11 full 128 wide, tile 12 is 64 wide (static 4-ns branch; OOB B-tile rows
// read adjacent workspace — in-bounds, never consumed). Accumulation order identical
// to the 64x64 version (bit-identical output).

__global__ __launch_bounds__(512) void gemm_bt(const u16* __restrict__ A, const u16* __restrict__ W,
                                               const float* __restrict__ bias, u16* __restrict__ C,
                                               int Ks) {
  __shared__ __align__(16) u16 As[128 * 72];  // stride 72 shorts = 144 B (8 start-banks, b128-clean)
  __shared__ __align__(16) u16 Bs[128 * 72];
  int tid = threadIdx.x;
  int n0 = blockIdx.x * 128, m0 = blockIdx.y * 128;
  int lane = tid & 63, wv = tid >> 6, ln = lane & 15, quad = lane >> 4;
  floatx4 acc[8] = {{0.f, 0.f, 0.f, 0.f}, {0.f, 0.f, 0.f, 0.f}, {0.f, 0.f, 0.f, 0.f}, {0.f, 0.f, 0.f, 0.f},
                    {0.f, 0.f, 0.f, 0.f}, {0.f, 0.f, 0.f, 0.f}, {0.f, 0.f, 0.f, 0.f}, {0.f, 0.f, 0.f, 0.f}};
  int arow = tid >> 2, acs = (tid & 3) * 8;  // thread covers cols [acs,acs+8) and [acs+32,acs+40)
  const u16* Ag = A + (size_t)(m0 + arow) * Ks + acs;
  const u16* Wg = W + (size_t)(n0 + arow) * Ks + acs;
  int asb = arow * 72 + acs;
  uint4 ra0 = *(const uint4*)(Ag);
  uint4 ra1 = *(const uint4*)(Ag + 32);
  uint4 rb0 = *(const uint4*)(Wg);
  uint4 rb1 = *(const uint4*)(Wg + 32);
  const bool full = (n0 + 128 <= NG);  // uniform per block
  for (int k0 = 0; k0 < Ks; k0 += 64) {
    *(uint4*)&As[asb] = ra0;
    *(uint4*)&As[asb + 32] = ra1;
    *(uint4*)&Bs[asb] = rb0;
    *(uint4*)&Bs[asb + 32] = rb1;
    __syncthreads();
    if (k0 + 64 < Ks) {  // prefetch next chunk; consumed at next iteration's store
      ra0 = *(const uint4*)(Ag + k0 + 64);
      ra1 = *(const uint4*)(Ag + k0 + 96);
      rb0 = *(const uint4*)(Wg + k0 + 64);
      rb1 = *(const uint4*)(Wg + k0 + 96);
    }
    int abase = (wv * 16 + ln) * 72;
    if (full) {
#pragma unroll
      for (int ks = 0; ks < 2; ++ks) {
        int ko = ks * 32 + quad * 8;
        shortx8 af = *(const shortx8*)&As[abase + ko];
#pragma unroll
        for (int ns = 0; ns < 8; ++ns) {
          shortx8 bf = *(const shortx8*)&Bs[(ns * 16 + ln) * 72 + ko];
          acc[ns] = __builtin_amdgcn_mfma_f32_16x16x32_bf16(af, bf, acc[ns], 0, 0, 0);
        }
      }
    } else {
#pragma unroll
      for (int ks = 0; ks < 2; ++ks) {
        int ko = ks * 32 + quad * 8;
        shortx8 af = *(const shortx8*)&As[abase + ko];
#pragma unroll
        for (int ns = 0; ns < 4; ++ns) {
          shortx8 bf = *(const shortx8*)&Bs[(ns * 16 + ln) * 72 + ko];
          acc[ns] = __builtin_amdgcn_mfma_f32_16x16x32_bf16(af, bf, acc[ns], 0, 0, 0);
        }
      }
    }
    __syncthreads();
  }
  int rbase = m0 + wv * 16 + quad * 4;  // C/D: col=lane&15, row=quad*4+reg (m89-verified)
  if (full) {
#pragma unroll
    for (int ns = 0; ns < 8; ++ns) {
      int cg = n0 + ns * 16 + ln;
      float bv = bias[cg];
#pragma unroll
      for (int r = 0; r < 4; ++r) {
        C[(size_t)(rbase + r) * NG + cg] = f2bf(acc[ns][r] + bv);
      }
    }
  } else {
#pragma unroll
    for (int ns = 0; ns < 4; ++ns) {
      int cg = n0 + ns * 16 + ln;
      float bv = bias[cg];
#pragma unroll
      for (int r = 0; r < 4; ++r) {
        C[(size_t)(rbase + r) * NG + cg] = f2bf(acc[ns][r] + bv);
      }
    }
  }
}

// ---------- recurrence: 64 blocks = (batch, dir), weights VGPR-resident ----------
// Per step: prefetch xg[t+1] (hides L2/HBM latency behind the 100-deep fdot2 chain),
// 4 independent accumulator chains, h broadcast via LDS (f16).
// Layer 0: threads 256..303 (idle during activation) zero-pad x1 cols 400..447.
// launch_bounds(448) WITHOUT min-waves: 64 blocks never co-reside (256 CUs), and the
// 256-VGPR cap from (448,2) is within ~16 regs of rec's live set (round-4 spill evidence).

__global__ __launch_bounds__(448) void rec_kernel(const u16* __restrict__ xg, const u16* __restrict__ Whf,
                                                  int layer, u16* __restrict__ x1, float* __restrict__ hs) {
  int tid = threadIdx.x;
  int batch = blockIdx.x >> 1, dir = blockIdx.x & 1;
  __shared__ __align__(16) u16 hsh[H_];   // h as f16
  __shared__ float gsh[800];
  uint4 wA[25], wB[25];                   // 2 rows x 200 f16 = 200 VGPRs
  if (tid < 400) {
    const uint4* wa = (const uint4*)(Whf + (size_t)((layer * 2 + dir) * 800 + tid) * 200);
    const uint4* wb = (const uint4*)(Whf + (size_t)((layer * 2 + dir) * 800 + tid + 400) * 200);
#pragma unroll
    for (int i = 0; i < 25; ++i) { wA[i] = wa[i]; wB[i] = wb[i]; }
  }
  float cst = 0.f;
  if (tid < H_) hsh[tid] = 0;
  int rstep = (dir ? -B_ : B_) * NG;
  const u16* xr = xg + (size_t)((dir ? (L_ - 1) * B_ : 0) + batch) * NG + dir * 800;
  float a0 = 0.f, a1 = 0.f;
  if (tid < 400) { a0 = bf2f(xr[tid]); a1 = bf2f(xr[tid + 400]); }
  __syncthreads();
  for (int t = 0; t < L_; ++t) {
    int tt = dir ? (L_ - 1 - t) : t;
    float n0 = 0.f, n1 = 0.f;
    if (tid < 400) {
      if (t + 1 < L_) {  // prefetch next step's xg before the dot chain
        const u16* xn = xr + (ptrdiff_t)(t + 1) * rstep;
        n0 = bf2f(xn[tid]);
        n1 = bf2f(xn[tid + 400]);
      }
      float c0 = 0.f, c1 = 0.f;  // second accumulator pair (shorter dep chains)
      const uint4* hv4 = (const uint4*)hsh;
#pragma unroll
      for (int kk = 0; kk < 25; kk += 2) {
        uint4 hv = hv4[kk];  // broadcast read (free)
        a0 = dot2h(wA[kk].x, hv.x, a0);
        a0 = dot2h(wA[kk].y, hv.y, a0);
        a0 = dot2h(wA[kk].z, hv.z, a0);
        a0 = dot2h(wA[kk].w, hv.w, a0);
        a1 = dot2h(wB[kk].x, hv.x, a1);
        a1 = dot2h(wB[kk].y, hv.y, a1);
        a1 = dot2h(wB[kk].z, hv.z, a1);
        a1 = dot2h(wB[kk].w, hv.w, a1);
        if (kk + 1 < 25) {
          uint4 hw = hv4[kk + 1];
          c0 = dot2h(wA[kk + 1].x, hw.x, c0);
          c0 = dot2h(wA[kk + 1].y, hw.y, c0);
          c0 = dot2h(wA[kk + 1].z, hw.z, c0);
          c0 = dot2h(wA[kk + 1].w, hw.w, c0);
          c1 = dot2h(wB[kk + 1].x, hw.x, c1);
          c1 = dot2h(wB[kk + 1].y, hw.y, c1);
          c1 = dot2h(wB[kk + 1].z, hw.z, c1);
          c1 = dot2h(wB[kk + 1].w, hw.w, c1);
        }
      }
      gsh[tid] = a0 + c0;
      gsh[tid + 400] = a1 + c1;
    }
    __syncthreads();
    int orow = tt * B_ + batch;
    if (tid < H_) {
      float gi = gsh[tid], gf = gsh[200 + tid], gg = gsh[400 + tid], go = gsh[600 + tid];
      cst = sigf(gf) * cst + sigf(gi) * tanhff(gg);
      float h = sigf(go) * tanhff(cst);
      _Float16 hh = (_Float16)h;
      hsh[tid] = __builtin_bit_cast(u16, hh);
      if (layer == 0) {
        x1[(size_t)orow * K1P + dir * H_ + tid] = f2bf(h);
      } else {
        hs[(size_t)orow * 400 + dir * H_ + tid] = h;
      }
    } else if (layer == 0 && tid >= 256 && tid < 256 + 48) {
      x1[(size_t)orow * K1P + 400 + (tid - 256)] = (u16)0;  // pad cols for K=448 GEMM
    }
    a0 = n0;
    a1 = n1;
    __syncthreads();
  }
}

// ---------- span output: out[bb][p][0:400], 8 cols per thread (16B loads/stores) ----------
// Grid is (bb=32, chunk=126): linear block id = bb + 32*chunk, and 32%8==0, so XCD = bb%8.
// Each XCD serves only 4 batches -> 816 KB of hs1 slices, L2-resident across all 126 chunks.

__global__ __launch_bounds__(256) void span_kernel(const float* __restrict__ hs, const int* __restrict__ pa,
                                                   const int* __restrict__ pb, void* __restrict__ outp,
                                                   const int* __restrict__ flag) {
  int bb = blockIdx.x;
  int p0 = blockIdx.y * 64;
  int isf32 = *flag;
  for (int idx = threadIdx.x; idx < 64 * 50; idx += 256) {
    int pr = idx / 50;           // pair within block chunk
    int q = idx - pr * 50;       // 8-col group: cols 8q..8q+7
    int p = p0 + pr;
    if (p >= NPAIR) continue;
    int a = pa[p], b = pb[p];
    int fwd = (q < 25);          // cols<200 -> f[b]-f[a]; cols>=200 -> bw[a+1]-bw[b+1]
    int r1 = fwd ? b : (a + 1);
    int r2 = fwd ? a : (b + 1);
    int col = q * 8;
    const fx4* h1 = (const fx4*)(hs + (size_t)(r1 * B_ + bb) * 400 + col);
    const fx4* h2 = (const fx4*)(hs + (size_t)(r2 * B_ + bb) * 400 + col);
    fx4 d0 = h1[0] - h2[0];
    fx4 d1 = h1[1] - h2[1];
    if (isf32) {
      fx4* o = (fx4*)outp + (size_t)(bb * NPAIR + p) * 100 + q * 2;
      o[0] = d0;
      o[1] = d1;
    } else {
      ux4 w;
      w.x = (u32)f2bf(d0.x) | ((u32)f2bf(d0.y) << 16);
      w.y = (u32)f2bf(d0.z) | ((u32)f2bf(d0.w) << 16);
      w.z = (u32)f2bf(d1.x) | ((u32)f2bf(d1.y) << 16);
      w.w = (u32)f2bf(d1.z) | ((u32)f2bf(d1.w) << 16);
      ((ux4*)outp)[(size_t)(bb * NPAIR + p) * 50 + q] = w;
    }
  }
}

// ---------- launch ----------

extern "C" void kernel_launch(void* const* d_in, const int* in_sizes, int n_in,
                              void* d_out, int out_size, void* d_ws, size_t ws_size,
                              hipStream_t stream) {
  const int* lang = (const int*)d_in[0];
  const int* word = (const int*)d_in[1];
  const int* pos = (const int*)d_in[2];
  const int* dep = (const int*)d_in[3];
  const int* ent = (const int*)d_in[4];
  const int* iob = (const int*)d_in[5];

  char* ws = (char*)d_ws;
  int* flag = (int*)(ws + 0);
  int* pa = (int*)(ws + 4096);
  int* pb = (int*)(ws + 36864);
  u16* x0 = (u16*)(ws + 69632);            // 4096x576 bf16 (4,718,592 B)
  u16* x1 = x0;                            // aliased: x0 dead after gemm0; x1 = 4096x448 bf16 fits
  u16* Wc0 = (u16*)(ws + 4788224);         // 1600x576 bf16
  u16* Wc1 = (u16*)(ws + 6631424);         // 1600x448 bf16
  float* bias0 = (float*)(ws + 8065024);   // 1600 f32
  float* bias1 = (float*)(ws + 8071424);
  u16* Whf = (u16*)(ws + 8077824);         // 2x2x800x200 f16
  float* hs1 = (float*)(ws + 9357824);     // 4096x400 f32
  u16* xg = (u16*)(ws + 15911424);         // 4096x1600 bf16 (end ~29.0 MB)

  hipLaunchKernelGGL(setup_kernel, dim3(EMB_BLKS + PACK_BLKS + 1), dim3(256), 0, stream,
                     lang, word, pos, dep, ent, iob,
                     d_in[6], d_in[7], d_in[8], d_in[9], d_in[10], d_in[11],
                     d_in[12], d_in[13], d_in[14], d_in[15],
                     d_in[16], d_in[17], d_in[18], d_in[19],
                     x0, Wc0, Wc1, bias0, bias1, Whf, flag, pa, pb, d_out);
  hipLaunchKernelGGL(gemm_bt, dim3(13, 32), dim3(512), 0, stream, x0, Wc0, bias0, xg, K0P);
  hipLaunchKernelGGL(rec_kernel, dim3(64), dim3(448), 0, stream, xg, Whf, 0, x1, hs1);
  hipLaunchKernelGGL(gemm_bt, dim3(13, 32), dim3(512), 0, stream, x1, Wc1, bias1, xg, K1P);
  hipLaunchKernelGGL(rec_kernel, dim3(64), dim3(448), 0, stream, xg, Whf, 1, x1, hs1);
  hipLaunchKernelGGL(span_kernel, dim3(32, 126), dim3(256), 0, stream, hs1, pa, pb, d_out, flag);
}

// Round 6
// 912.425 us; speedup vs baseline: 1.1310x; 1.0145x over previous
//
#include <hip/hip_runtime.h>
#include <hip/hip_bf16.h>
#include <hip/hip_fp16.h>

// LSTM_Encoder pipeline (dtype-agnostic: runtime-sniffs fp32 vs bf16 inputs):
//   setup (fused embed+pack+pairs+senlen; sniff 64-sample on thread 0, LDS-broadcast;
//          embed float2/u32 vector loads; pack 4 elem/thread vectorized -> 2229 blocks)
//   gemm_bt(x0,Wc0) -> xg    (MFMA bf16, M=4096 N=1600 K=576; 128x128 tile, BK=64,
//                             reg-prefetch pipeline; last N-tile is 64-wide via 'full' branch)
//   rec(layer0)              (64 blocks = batch x dir, VGPR-resident f16 weights,
//                             xg prefetched one step ahead; idle lanes zero-pad x1 cols 400..447.
//                             2-barrier gsh form is FINAL: pair-exchange variant needs >256 VGPR
//                             -> spills under (448,2) cap (round4 +109us) and can't schedule a
//                             7-wave block uncapped. launch_bounds(448) no min-waves (round5 ok).)
//   gemm_bt(x1,Wc1) -> xg    (K=448 padded)
//   rec(layer1) -> hs1 (f32)
//   span                     (grid transposed (bb,chunk): 32%8==0 pins batch bb to XCD bb%8,
//                             hs1 slice 816 KB/XCD stays L2-resident; regular 16B stores —
//                             NT stores measured ~+60us on this stream (round1), do not retry)

typedef unsigned short u16;
typedef unsigned int u32;
typedef short shortx8 __attribute__((ext_vector_type(8)));
typedef float floatx4 __attribute__((ext_vector_type(4)));
typedef float fx4 __attribute__((ext_vector_type(4)));
typedef unsigned int ux4 __attribute__((ext_vector_type(4)));
typedef _Float16 half2v __attribute__((ext_vector_type(2)));

#define B_ 32
#define L_ 128
#define H_ 200
#define K0P 576
#define K1P 448
#define NG 1600
#define NPAIR 8001
#define SPAN_ELEMS 102412800  // 32*8001*400

#define EMB_BLKS 1024
#define PACK_ELEMS (1600 * K0P + 1600 * K1P + 1600 + 1600 + 640000)  // 2,281,600 (div 4)
#define PACK_BLKS ((PACK_ELEMS / 4 + 255) / 256)                     // 4 elems/thread -> 2229

__device__ __forceinline__ float bf2f(u16 v) {
  u32 u = ((u32)v) << 16;
  return __builtin_bit_cast(float, u);
}
__device__ __forceinline__ u16 f2bf(float f) {
  __hip_bfloat16 h = __float2bfloat16(f);
  return __builtin_bit_cast(u16, h);
}
__device__ __forceinline__ float loadF(const void* p, int idx, int isf32) {
  return isf32 ? ((const float*)p)[idx] : bf2f(((const u16*)p)[idx]);
}
__device__ __forceinline__ float dot2h(u32 w, u32 h, float acc) {
#if __has_builtin(__builtin_amdgcn_fdot2)
  return __builtin_amdgcn_fdot2(__builtin_bit_cast(half2v, w),
                                __builtin_bit_cast(half2v, h), acc, false);
#else
  half2v a = __builtin_bit_cast(half2v, w), b = __builtin_bit_cast(half2v, h);
  return acc + (float)a.x * (float)b.x + (float)a.y * (float)b.y;
#endif
}
__device__ __forceinline__ float sigf(float x) { return 1.f / (1.f + __expf(-x)); }
__device__ __forceinline__ float tanhff(float x) {
  x = fminf(fmaxf(x, -15.f), 15.f);
  float e = __expf(-2.f * x);
  return (1.f - e) / (1.f + e);
}

// dtype sniff: |bf16| >= 32 never for 0.1*N(0,1) bf16 data (exp field < 0x84 always);
// fp32-as-u16-halves: low halves have ~48% (v>>7)&0xFF >= 0x84 -> ~15 of 32 lows fire.
// 64 samples, threshold 4: deterministic pass for both dtypes, half the round-1 cost.
__device__ __forceinline__ int sniff(const u16* p) {
  int big = 0;
#pragma unroll 16
  for (int i = 0; i < 64; ++i) {
    int e = (p[i] >> 7) & 0xFF;
    big += (e >= 0x84);
  }
  return (big >= 4) ? 1 : 0;
}

// ---------- fused setup: embed (blocks 0..1023) / pack / pairs+senlen+flag (last block) ----------
// sniff once per block on thread 0, LDS-broadcast. All payload loads vectorized (G13):
// embed float2/u32 (segment strides 50/300 even -> 8B-aligned), pack float4/float2/ushort4
// per-section (Wih0's 550-stride is only 8B-aligned; Wih1/Whh/bias are 16B-clean).

__global__ void setup_kernel(const int* __restrict__ lang, const int* __restrict__ word,
                             const int* __restrict__ pos, const int* __restrict__ dep,
                             const int* __restrict__ ent, const int* __restrict__ iob,
                             const void* __restrict__ El, const void* __restrict__ Ew,
                             const void* __restrict__ Ep, const void* __restrict__ Ed,
                             const void* __restrict__ Ee, const void* __restrict__ Ei,
                             const void* __restrict__ Wih0, const void* __restrict__ Whh0,
                             const void* __restrict__ bih0, const void* __restrict__ bhh0,
                             const void* __restrict__ Wih1, const void* __restrict__ Whh1,
                             const void* __restrict__ bih1, const void* __restrict__ bhh1,
                             u16* __restrict__ x0, u16* __restrict__ Wc0, u16* __restrict__ Wc1,
                             float* __restrict__ bias0, float* __restrict__ bias1,
                             u16* __restrict__ Whf, int* __restrict__ flag,
                             int* __restrict__ pa, int* __restrict__ pb, void* __restrict__ out) {
  __shared__ int sflag;
  int blk = blockIdx.x, tid = threadIdx.x;
  if (tid == 0) sflag = sniff((const u16*)Ew);
  __syncthreads();
  int isf32 = sflag;

  if (blk < EMB_BLKS) {  // embedding gather: 4 rows/block, row = l*32 + b; col-PAIR per lane iter
    int row = blk * 4 + (tid >> 6);
    int lane = tid & 63;
    int l = row >> 5, b = row & 31;
    int io = b * L_ + l;
    int li = lang[io], wi = word[io], pi = pos[io], di = dep[io], ei = ent[io], ii = iob[io];
    u32* xo = (u32*)&x0[row * K0P];  // row*576 even -> 4B-aligned
    for (int cp = lane; cp < 288; cp += 64) {  // 288 col-pairs (576 cols)
      int c = cp * 2;
      float v0 = 0.f, v1 = 0.f;
      const void* src = nullptr;
      int off = 0;
      if (c < 50) { src = El; off = li * 50 + c; }
      else if (c < 350) { src = Ew; off = wi * 300 + (c - 50); }
      else if (c < 400) { src = Ep; off = pi * 50 + (c - 350); }
      else if (c < 450) { src = Ed; off = di * 50 + (c - 400); }
      else if (c < 500) { src = Ee; off = ei * 50 + (c - 450); }
      else if (c < 550) { src = Ei; off = ii * 50 + (c - 500); }
      if (src) {  // off always even; pair never straddles a segment (boundaries even)
        if (isf32) {
          float2 v = *((const float2*)src + (off >> 1));
          v0 = v.x; v1 = v.y;
        } else {
          u32 w = *((const u32*)src + (off >> 1));
          v0 = bf2f((u16)w); v1 = bf2f((u16)(w >> 16));
        }
      }
      xo[cp] = (u32)f2bf(v0) | ((u32)f2bf(v1) << 16);
    }
    return;
  }
  blk -= EMB_BLKS;

  if (blk < PACK_BLKS) {  // weight repack, 4 consecutive elements per thread
    int q4 = (blk * 256 + tid) * 4;
    if (q4 >= PACK_ELEMS) return;
    if (q4 < 1600 * K0P) {  // Wc0: rows (dir*800+g), cols padded 550->576; K0P div4 -> quad in-row
      int r = q4 / K0P, c = q4 - r * K0P;  // c div 4
      u16 o0, o1, o2, o3;
      if (c + 3 < 550) {  // src offset r*550+c is even -> 8B-aligned; NOT div4 (550%4=2), no 16B
        if (isf32) {
          const float* s = (const float*)Wih0 + (size_t)r * 550 + c;
          float2 va = *(const float2*)s, vb = *(const float2*)(s + 2);
          o0 = f2bf(va.x); o1 = f2bf(va.y); o2 = f2bf(vb.x); o3 = f2bf(vb.y);
        } else {
          const u32* s = (const u32*)Wih0 + (((size_t)r * 550 + c) >> 1);
          u32 wa = s[0], wb = s[1];
          o0 = (u16)wa; o1 = (u16)(wa >> 16); o2 = (u16)wb; o3 = (u16)(wb >> 16);
        }
      } else {  // quad touching the 550 pad boundary (c=548) or fully pad
        o0 = (c + 0 < 550) ? f2bf(loadF(Wih0, r * 550 + c + 0, isf32)) : (u16)0;
        o1 = (c + 1 < 550) ? f2bf(loadF(Wih0, r * 550 + c + 1, isf32)) : (u16)0;
        o2 = (c + 2 < 550) ? f2bf(loadF(Wih0, r * 550 + c + 2, isf32)) : (u16)0;
        o3 = (c + 3 < 550) ? f2bf(loadF(Wih0, r * 550 + c + 3, isf32)) : (u16)0;
      }
      *(ushort4*)&Wc0[q4] = make_ushort4(o0, o1, o2, o3);
      return;
    }
    q4 -= 1600 * K0P;
    if (q4 < 1600 * K1P) {  // Wc1: cols padded 400->448; 400 div4 -> quads all-real or all-pad
      int r = q4 / K1P, c = q4 - r * K1P;  // c div 4
      ushort4 o = make_ushort4(0, 0, 0, 0);
      if (c < 400) {  // src offset r*400+c div 4 -> 16B-aligned
        if (isf32) {
          fx4 v = *(const fx4*)((const float*)Wih1 + (size_t)r * 400 + c);
          o = make_ushort4(f2bf(v.x), f2bf(v.y), f2bf(v.z), f2bf(v.w));
        } else {
          ushort4 v = *(const ushort4*)((const u16*)Wih1 + (size_t)r * 400 + c);
          o = v;
        }
      }
      *(ushort4*)&Wc1[q4] = o;
      return;
    }
    q4 -= 1600 * K1P;
    if (q4 < 1600) {  // bias0, 4 at a time (offsets div 4 -> 16B-aligned f32 path)
      fx4 o;
      if (isf32) {
        fx4 a = *(const fx4*)((const float*)bih0 + q4);
        fx4 b = *(const fx4*)((const float*)bhh0 + q4);
        o = a + b;
      } else {
        ushort4 a = *(const ushort4*)((const u16*)bih0 + q4);
        ushort4 b = *(const ushort4*)((const u16*)bhh0 + q4);
        o.x = bf2f(a.x) + bf2f(b.x); o.y = bf2f(a.y) + bf2f(b.y);
        o.z = bf2f(a.z) + bf2f(b.z); o.w = bf2f(a.w) + bf2f(b.w);
      }
      *(fx4*)&bias0[q4] = o;
      return;
    }
    q4 -= 1600;
    if (q4 < 1600) {  // bias1
      fx4 o;
      if (isf32) {
        fx4 a = *(const fx4*)((const float*)bih1 + q4);
        fx4 b = *(const fx4*)((const float*)bhh1 + q4);
        o = a + b;
      } else {
        ushort4 a = *(const ushort4*)((const u16*)bih1 + q4);
        ushort4 b = *(const ushort4*)((const u16*)bhh1 + q4);
        o.x = bf2f(a.x) + bf2f(b.x); o.y = bf2f(a.y) + bf2f(b.y);
        o.z = bf2f(a.z) + bf2f(b.z); o.w = bf2f(a.w) + bf2f(b.w);
      }
      *(fx4*)&bias1[q4] = o;
      return;
    }
    q4 -= 1600;
    {  // Whh -> f16, [layer][dir][800][200]; in-section index div 4 -> 16B/8B aligned
      float s0, s1, s2, s3;
      if (q4 < 320000) {
        if (isf32) {
          fx4 v = *(const fx4*)((const float*)Whh0 + q4);
          s0 = v.x; s1 = v.y; s2 = v.z; s3 = v.w;
        } else {
          ushort4 v = *(const ushort4*)((const u16*)Whh0 + q4);
          s0 = bf2f(v.x); s1 = bf2f(v.y); s2 = bf2f(v.z); s3 = bf2f(v.w);
        }
      } else {
        int q = q4 - 320000;
        if (isf32) {
          fx4 v = *(const fx4*)((const float*)Whh1 + q);
          s0 = v.x; s1 = v.y; s2 = v.z; s3 = v.w;
        } else {
          ushort4 v = *(const ushort4*)((const u16*)Whh1 + q);
          s0 = bf2f(v.x); s1 = bf2f(v.y); s2 = bf2f(v.z); s3 = bf2f(v.w);
        }
      }
      _Float16 h0 = (_Float16)s0, h1 = (_Float16)s1, h2 = (_Float16)s2, h3 = (_Float16)s3;
      *(ushort4*)&Whf[q4] = make_ushort4(__builtin_bit_cast(u16, h0), __builtin_bit_cast(u16, h1),
                                         __builtin_bit_cast(u16, h2), __builtin_bit_cast(u16, h3));
    }
    return;
  }

  // final block: flag (for span), pairs, sen_lens
  if (tid == 0) *flag = isf32;
  if (tid < 126) {
    int a = tid;
    int off = a * 126 - a * (a - 1) / 2;
    for (int b = a + 1; b <= 126; ++b) {
      pa[off] = a;
      pb[off] = b;
      ++off;
    }
  }
  if (tid >= 128 && tid < 128 + B_) {
    int b = tid - 128;
    int cnt = 0;
    for (int l = 0; l < L_; ++l) cnt += (word[b * L_ + l] != 0);
    float v = (float)(cnt - 2);
    if (isf32) ((float*)out)[SPAN_ELEMS + b] = v;
    else ((u16*)out)[SPAN_ELEMS + b] = f2bf(v);
  }
}

// ---------- GEMM: C[M,1600](bf16) = A[M,Ks](bf16) * W[1600,Ks]^T + bias ----------
// 128x128 tile (8 waves, 512 thr), BK=64, reg-prefetch pipeline. Grid x=13 N-tiles:
// tiles 0..11 full 128 wide, tile 12 is 64 wide (static 4-ns branch; OOB B-tile rows
// read adjacent workspace — in-bounds, never consumed). Accumulation order identical
// to the 64x64 version (bit-identical output).

__global__ __launch_bounds__(512) void gemm_bt(const u16* __restrict__ A, const u16* __restrict__ W,
                                               const float* __restrict__ bias, u16* __restrict__ C,
                                               int Ks) {
  __shared__ __align__(16) u16 As[128 * 72];  // stride 72 shorts = 144 B (8 start-banks, b128-clean)
  __shared__ __align__(16) u16 Bs[128 * 72];
  int tid = threadIdx.x;
  int n0 = blockIdx.x * 128, m0 = blockIdx.y * 128;
  int lane = tid & 63, wv = tid >> 6, ln = lane & 15, quad = lane >> 4;
  floatx4 acc[8] = {{0.f, 0.f, 0.f, 0.f}, {0.f, 0.f, 0.f, 0.f}, {0.f, 0.f, 0.f, 0.f}, {0.f, 0.f, 0.f, 0.f},
                    {0.f, 0.f, 0.f, 0.f}, {0.f, 0.f, 0.f, 0.f}, {0.f, 0.f, 0.f, 0.f}, {0.f, 0.f, 0.f, 0.f}};
  int arow = tid >> 2, acs = (tid & 3) * 8;  // thread covers cols [acs,acs+8) and [acs+32,acs+40)
  const u16* Ag = A + (size_t)(m0 + arow) * Ks + acs;
  const u16* Wg = W + (size_t)(n0 + arow) * Ks + acs;
  int asb = arow * 72 + acs;
  uint4 ra0 = *(const uint4*)(Ag);
  uint4 ra1 = *(const uint4*)(Ag + 32);
  uint4 rb0 = *(const uint4*)(Wg);
  uint4 rb1 = *(const uint4*)(Wg + 32);
  const bool full = (n0 + 128 <= NG);  // uniform per block
  for (int k0 = 0; k0 < Ks; k0 += 64) {
    *(uint4*)&As[asb] = ra0;
    *(uint4*)&As[asb + 32] = ra1;
    *(uint4*)&Bs[asb] = rb0;
    *(uint4*)&Bs[asb + 32] = rb1;
    __syncthreads();
    if (k0 + 64 < Ks) {  // prefetch next chunk; consumed at next iteration's store
      ra0 = *(const uint4*)(Ag + k0 + 64);
      ra1 = *(const uint4*)(Ag + k0 + 96);
      rb0 = *(const uint4*)(Wg + k0 + 64);
      rb1 = *(const uint4*)(Wg + k0 + 96);
    }
    int abase = (wv * 16 + ln) * 72;
    if (full) {
#pragma unroll
      for (int ks = 0; ks < 2; ++ks) {
        int ko = ks * 32 + quad * 8;
        shortx8 af = *(const shortx8*)&As[abase + ko];
#pragma unroll
        for (int ns = 0; ns < 8; ++ns) {
          shortx8 bf = *(const shortx8*)&Bs[(ns * 16 + ln) * 72 + ko];
          acc[ns] = __builtin_amdgcn_mfma_f32_16x16x32_bf16(af, bf, acc[ns], 0, 0, 0);
        }
      }
    } else {
#pragma unroll
      for (int ks = 0; ks < 2; ++ks) {
        int ko = ks * 32 + quad * 8;
        shortx8 af = *(const shortx8*)&As[abase + ko];
#pragma unroll
        for (int ns = 0; ns < 4; ++ns) {
          shortx8 bf = *(const shortx8*)&Bs[(ns * 16 + ln) * 72 + ko];
          acc[ns] = __builtin_amdgcn_mfma_f32_16x16x32_bf16(af, bf, acc[ns], 0, 0, 0);
        }
      }
    }
    __syncthreads();
  }
  int rbase = m0 + wv * 16 + quad * 4;  // C/D: col=lane&15, row=quad*4+reg (m89-verified)
  if (full) {
#pragma unroll
    for (int ns = 0; ns < 8; ++ns) {
      int cg = n0 + ns * 16 + ln;
      float bv = bias[cg];
#pragma unroll
      for (int r = 0; r < 4; ++r) {
        C[(size_t)(rbase + r) * NG + cg] = f2bf(acc[ns][r] + bv);
      }
    }
  } else {
#pragma unroll
    for (int ns = 0; ns < 4; ++ns) {
      int cg = n0 + ns * 16 + ln;
      float bv = bias[cg];
#pragma unroll
      for (int r = 0; r < 4; ++r) {
        C[(size_t)(rbase + r) * NG + cg] = f2bf(acc[ns][r] + bv);
      }
    }
  }
}

// ---------- recurrence: 64 blocks = (batch, dir), weights VGPR-resident ----------
// Per step: prefetch xg[t+1] (hides L2/HBM latency behind the 100-deep fdot2 chain),
// 4 independent accumulator chains, h broadcast via LDS (f16).
// Layer 0: threads 256..303 (idle during activation) zero-pad x1 cols 400..447.
// 2-barrier gsh structure is FINAL (see header note); launch_bounds(448) uncapped.

__global__ __launch_bounds__(448) void rec_kernel(const u16* __restrict__ xg, const u16* __restrict__ Whf,
                                                  int layer, u16* __restrict__ x1, float* __restrict__ hs) {
  int tid = threadIdx.x;
  int batch = blockIdx.x >> 1, dir = blockIdx.x & 1;
  __shared__ __align__(16) u16 hsh[H_];   // h as f16
  __shared__ float gsh[800];
  uint4 wA[25], wB[25];                   // 2 rows x 200 f16 = 200 VGPRs
  if (tid < 400) {
    const uint4* wa = (const uint4*)(Whf + (size_t)((layer * 2 + dir) * 800 + tid) * 200);
    const uint4* wb = (const uint4*)(Whf + (size_t)((layer * 2 + dir) * 800 + tid + 400) * 200);
#pragma unroll
    for (int i = 0; i < 25; ++i) { wA[i] = wa[i]; wB[i] = wb[i]; }
  }
  float cst = 0.f;
  if (tid < H_) hsh[tid] = 0;
  int rstep = (dir ? -B_ : B_) * NG;
  const u16* xr = xg + (size_t)((dir ? (L_ - 1) * B_ : 0) + batch) * NG + dir * 800;
  float a0 = 0.f, a1 = 0.f;
  if (tid < 400) { a0 = bf2f(xr[tid]); a1 = bf2f(xr[tid + 400]); }
  __syncthreads();
  for (int t = 0; t < L_; ++t) {
    int tt = dir ? (L_ - 1 - t) : t;
    float n0 = 0.f, n1 = 0.f;
    if (tid < 400) {
      if (t + 1 < L_) {  // prefetch next step's xg before the dot chain
        const u16* xn = xr + (ptrdiff_t)(t + 1) * rstep;
        n0 = bf2f(xn[tid]);
        n1 = bf2f(xn[tid + 400]);
      }
      float c0 = 0.f, c1 = 0.f;  // second accumulator pair (shorter dep chains)
      const uint4* hv4 = (const uint4*)hsh;
#pragma unroll
      for (int kk = 0; kk < 25; kk += 2) {
        uint4 hv = hv4[kk];  // broadcast read (free)
        a0 = dot2h(wA[kk].x, hv.x, a0);
        a0 = dot2h(wA[kk].y, hv.y, a0);
        a0 = dot2h(wA[kk].z, hv.z, a0);
        a0 = dot2h(wA[kk].w, hv.w, a0);
        a1 = dot2h(wB[kk].x, hv.x, a1);
        a1 = dot2h(wB[kk].y, hv.y, a1);
        a1 = dot2h(wB[kk].z, hv.z, a1);
        a1 = dot2h(wB[kk].w, hv.w, a1);
        if (kk + 1 < 25) {
          uint4 hw = hv4[kk + 1];
          c0 = dot2h(wA[kk + 1].x, hw.x, c0);
          c0 = dot2h(wA[kk + 1].y, hw.y, c0);
          c0 = dot2h(wA[kk + 1].z, hw.z, c0);
          c0 = dot2h(wA[kk + 1].w, hw.w, c0);
          c1 = dot2h(wB[kk + 1].x, hw.x, c1);
          c1 = dot2h(wB[kk + 1].y, hw.y, c1);
          c1 = dot2h(wB[kk + 1].z, hw.z, c1);
          c1 = dot2h(wB[kk + 1].w, hw.w, c1);
        }
      }
      gsh[tid] = a0 + c0;
      gsh[tid + 400] = a1 + c1;
    }
    __syncthreads();
    int orow = tt * B_ + batch;
    if (tid < H_) {
      float gi = gsh[tid], gf = gsh[200 + tid], gg = gsh[400 + tid], go = gsh[600 + tid];
      cst = sigf(gf) * cst + sigf(gi) * tanhff(gg);
      float h = sigf(go) * tanhff(cst);
      _Float16 hh = (_Float16)h;
      hsh[tid] = __builtin_bit_cast(u16, hh);
      if (layer == 0) {
        x1[(size_t)orow * K1P + dir * H_ + tid] = f2bf(h);
      } else {
        hs[(size_t)orow * 400 + dir * H_ + tid] = h;
      }
    } else if (layer == 0 && tid >= 256 && tid < 256 + 48) {
      x1[(size_t)orow * K1P + 400 + (tid - 256)] = (u16)0;  // pad cols for K=448 GEMM
    }
    a0 = n0;
    a1 = n1;
    __syncthreads();
  }
}

// ---------- span output: out[bb][p][0:400], 8 cols per thread (16B loads/stores) ----------
// Grid is (bb=32, chunk=126): linear block id = bb + 32*chunk, and 32%8==0, so XCD = bb%8.
// Each XCD serves only 4 batches -> 816 KB of hs1 slices, L2-resident across all 126 chunks.

__global__ __launch_bounds__(256) void span_kernel(const float* __restrict__ hs, const int* __restrict__ pa,
                                                   const int* __restrict__ pb, void* __restrict__ outp,
                                                   const int* __restrict__ flag) {
  int bb = blockIdx.x;
  int p0 = blockIdx.y * 64;
  int isf32 = *flag;
  for (int idx = threadIdx.x; idx < 64 * 50; idx += 256) {
    int pr = idx / 50;           // pair within block chunk
    int q = idx - pr * 50;       // 8-col group: cols 8q..8q+7
    int p = p0 + pr;
    if (p >= NPAIR) continue;
    int a = pa[p], b = pb[p];
    int fwd = (q < 25);          // cols<200 -> f[b]-f[a]; cols>=200 -> bw[a+1]-bw[b+1]
    int r1 = fwd ? b : (a + 1);
    int r2 = fwd ? a : (b + 1);
    int col = q * 8;
    const fx4* h1 = (const fx4*)(hs + (size_t)(r1 * B_ + bb) * 400 + col);
    const fx4* h2 = (const fx4*)(hs + (size_t)(r2 * B_ + bb) * 400 + col);
    fx4 d0 = h1[0] - h2[0];
    fx4 d1 = h1[1] - h2[1];
    if (isf32) {
      fx4* o = (fx4*)outp + (size_t)(bb * NPAIR + p) * 100 + q * 2;
      o[0] = d0;
      o[1] = d1;
    } else {
      ux4 w;
      w.x = (u32)f2bf(d0.x) | ((u32)f2bf(d0.y) << 16);
      w.y = (u32)f2bf(d0.z) | ((u32)f2bf(d0.w) << 16);
      w.z = (u32)f2bf(d1.x) | ((u32)f2bf(d1.y) << 16);
      w.w = (u32)f2bf(d1.z) | ((u32)f2bf(d1.w) << 16);
      ((ux4*)outp)[(size_t)(bb * NPAIR + p) * 50 + q] = w;
    }
  }
}

// ---------- launch ----------

extern "C" void kernel_launch(void* const* d_in, const int* in_sizes, int n_in,
                              void* d_out, int out_size, void* d_ws, size_t ws_size,
                              hipStream_t stream) {
  const int* lang = (const int*)d_in[0];
  const int* word = (const int*)d_in[1];
  const int* pos = (const int*)d_in[2];
  const int* dep = (const int*)d_in[3];
  const int* ent = (const int*)d_in[4];
  const int* iob = (const int*)d_in[5];

  char* ws = (char*)d_ws;
  int* flag = (int*)(ws + 0);
  int* pa = (int*)(ws + 4096);
  int* pb = (int*)(ws + 36864);
  u16* x0 = (u16*)(ws + 69632);            // 4096x576 bf16 (4,718,592 B)
  u16* x1 = x0;                            // aliased: x0 dead after gemm0; x1 = 4096x448 bf16 fits
  u16* Wc0 = (u16*)(ws + 4788224);         // 1600x576 bf16
  u16* Wc1 = (u16*)(ws + 6631424);         // 1600x448 bf16
  float* bias0 = (float*)(ws + 8065024);   // 1600 f32
  float* bias1 = (float*)(ws + 8071424);
  u16* Whf = (u16*)(ws + 8077824);         // 2x2x800x200 f16
  float* hs1 = (float*)(ws + 9357824);     // 4096x400 f32
  u16* xg = (u16*)(ws + 15911424);         // 4096x1600 bf16 (end ~29.0 MB)

  hipLaunchKernelGGL(setup_kernel, dim3(EMB_BLKS + PACK_BLKS + 1), dim3(256), 0, stream,
                     lang, word, pos, dep, ent, iob,
                     d_in[6], d_in[7], d_in[8], d_in[9], d_in[10], d_in[11],
                     d_in[12], d_in[13], d_in[14], d_in[15],
                     d_in[16], d_in[17], d_in[18], d_in[19],
                     x0, Wc0, Wc1, bias0, bias1, Whf, flag, pa, pb, d_out);
  hipLaunchKernelGGL(gemm_bt, dim3(13, 32), dim3(512), 0, stream, x0, Wc0, bias0, xg, K0P);
  hipLaunchKernelGGL(rec_kernel, dim3(64), dim3(448), 0, stream, xg, Whf, 0, x1, hs1);
  hipLaunchKernelGGL(gemm_bt, dim3(13, 32), dim3(512), 0, stream, x1, Wc1, bias1, xg, K1P);
  hipLaunchKernelGGL(rec_kernel, dim3(64), dim3(448), 0, stream, xg, Whf, 1, x1, hs1);
  hipLaunchKernelGGL(span_kernel, dim3(32, 126), dim3(256), 0, stream, hs1, pa, pb, d_out, flag);
}